// Round 1
// baseline (361.570 us; speedup 1.0000x reference)
//
#include <hip/hip_runtime.h>
#include <math.h>

// Problem constants (fixed by the reference): B=16, C=9, H=W=512.
#define NCLS 9
#define NB 16
#define HW (512 * 512)          // labels per sample
#define HW4 (HW / 4)            // float4s per (b,c) plane = 65536

// ---------------------------------------------------------------------------
// Kernel 1: per-sample 9-bin histogram.
// 1024 blocks x 256 threads; each thread consumes 16 labels via 4x int4.
// Each block's 4096-label chunk lies inside one sample (262144/4096 = 64
// blocks per sample), so sample = blockIdx.x / 64.
// Branchless register counters -> wave-64 shuffle reduce -> 9 atomics/wave.
// ---------------------------------------------------------------------------
__global__ void __launch_bounds__(256) hist_kernel(const int* __restrict__ labels,
                                                   int* __restrict__ hist) {
    const int tid = blockIdx.x * 256 + threadIdx.x;
    const int4* l4 = (const int4*)labels;
    const int base = tid * 4;           // int4 index

    int cnt[NCLS];
#pragma unroll
    for (int c = 0; c < NCLS; ++c) cnt[c] = 0;

#pragma unroll
    for (int j = 0; j < 4; ++j) {
        int4 v = l4[base + j];
#pragma unroll
        for (int c = 0; c < NCLS; ++c) {
            cnt[c] += (v.x == c) + (v.y == c) + (v.z == c) + (v.w == c);
        }
    }

    const int b = blockIdx.x >> 6;      // / 64 blocks-per-sample
#pragma unroll
    for (int c = 0; c < NCLS; ++c) {
        int s = cnt[c];
#pragma unroll
        for (int off = 32; off > 0; off >>= 1) s += __shfl_down(s, off);
        if ((threadIdx.x & 63) == 0 && s != 0) {
            atomicAdd(&hist[b * NCLS + c], s);
        }
    }
}

// ---------------------------------------------------------------------------
// Kernel 2: weights from histogram. One block, 192 threads (144 active).
// Thread t=(b,c) recomputes the per-sample stats redundantly (9 bins, trivial)
// and writes weight[b][c]. Matches the numpy reference:
//   p = h/total; logh = (h>0) ? -log(p) : 0
//   mean/std over bins with h>0 (population variance)
//   weight = (logh != 0) ? (logh-mean)/std*0.1 + 1.0 : 1.0
// ---------------------------------------------------------------------------
__global__ void __launch_bounds__(192) weight_kernel(const int* __restrict__ hist,
                                                     float* __restrict__ weight) {
    const int t = threadIdx.x;
    if (t >= NB * NCLS) return;
    const int b = t / NCLS;
    const int c = t % NCLS;

    float h[NCLS];
    float total = 0.f;
#pragma unroll
    for (int k = 0; k < NCLS; ++k) {
        h[k] = (float)hist[b * NCLS + k];
        total += h[k];
    }

    float logh[NCLS];
    float cntbins = 0.f, sum = 0.f;
#pragma unroll
    for (int k = 0; k < NCLS; ++k) {
        float p = h[k] / total;
        float lg = (h[k] > 0.f) ? -logf(p) : 0.f;
        logh[k] = lg;
        if (h[k] > 0.f) { cntbins += 1.f; sum += lg; }
    }
    const float mean = sum / cntbins;
    float var = 0.f;
#pragma unroll
    for (int k = 0; k < NCLS; ++k) {
        if (h[k] > 0.f) {
            float d = logh[k] - mean;
            var += d * d;
        }
    }
    var /= cntbins;
    const float stdv = sqrtf(var);

    const float lc = logh[c];
    weight[t] = (lc != 0.f) ? (lc - mean) / stdv * 0.1f + 1.0f : 1.0f;
}

// ---------------------------------------------------------------------------
// Kernel 3: out = preds * weight[plane], float4-vectorized grid-stride stream.
// plane = float4_index >> 16 because each (b,c) plane is 65536 float4s.
// ---------------------------------------------------------------------------
__global__ void __launch_bounds__(256) scale_kernel(const float4* __restrict__ in,
                                                    const float* __restrict__ weight,
                                                    float4* __restrict__ out,
                                                    int n4) {
    const int stride = gridDim.x * 256;
    for (int i = blockIdx.x * 256 + threadIdx.x; i < n4; i += stride) {
        const float w = weight[i >> 16];
        float4 v = in[i];
        v.x *= w; v.y *= w; v.z *= w; v.w *= w;
        out[i] = v;
    }
}

extern "C" void kernel_launch(void* const* d_in, const int* in_sizes, int n_in,
                              void* d_out, int out_size, void* d_ws, size_t ws_size,
                              hipStream_t stream) {
    const float* preds = (const float*)d_in[0];   // [16,9,512,512] f32
    const int* labels = (const int*)d_in[1];      // [16,512,512] i32
    float* out = (float*)d_out;

    // Workspace layout: hist (16*9 ints) | weight (16*9 floats)
    int* hist = (int*)d_ws;
    float* weight = (float*)((char*)d_ws + NB * NCLS * sizeof(int));

    // ws is poisoned to 0xAA each call: zero the histogram.
    hipMemsetAsync(hist, 0, NB * NCLS * sizeof(int), stream);

    // Histogram: 16 samples * 262144 labels / (256 thr * 16 lbl) = 1024 blocks
    hist_kernel<<<1024, 256, 0, stream>>>(labels, hist);

    // Weights: single small block.
    weight_kernel<<<1, 192, 0, stream>>>(hist, weight);

    // Scale: 37748736 floats -> 9437184 float4s, grid-stride at 2048 blocks.
    const int n4 = (NB * NCLS * HW) / 4;
    scale_kernel<<<2048, 256, 0, stream>>>((const float4*)preds, weight,
                                           (float4*)out, n4);
}

// Round 2
// 276.962 us; speedup vs baseline: 1.3055x; 1.3055x over previous
//
#include <hip/hip_runtime.h>
#include <math.h>

// Problem constants (fixed by the reference): B=16, C=9, H=W=512.
#define NCLS 9
#define NB 16
#define HW (512 * 512)          // labels per sample = 262144
#define NBLK_HIST 1024          // 64 hist blocks per sample
#define BLKS_PER_SAMPLE 64

// ---------------------------------------------------------------------------
// Kernel 1: per-block partial histograms -> partial[1024][9] (written, not
// accumulated: no zero-init, no atomics).
// 1024 blocks x 256 threads; each thread consumes 16 labels via 4x int4.
// Each block's 4096-label chunk lies inside one sample (262144/4096 = 64
// blocks per sample). Wave shuffle-reduce -> LDS -> 9 ints per block.
// ---------------------------------------------------------------------------
__global__ void __launch_bounds__(256) hist_kernel(const int* __restrict__ labels,
                                                   int* __restrict__ partial) {
    const int tid = blockIdx.x * 256 + threadIdx.x;
    const int4* l4 = (const int4*)labels;
    const int base = tid * 4;           // int4 index

    int cnt[NCLS];
#pragma unroll
    for (int c = 0; c < NCLS; ++c) cnt[c] = 0;

#pragma unroll
    for (int j = 0; j < 4; ++j) {
        int4 v = l4[base + j];
#pragma unroll
        for (int c = 0; c < NCLS; ++c) {
            cnt[c] += (v.x == c) + (v.y == c) + (v.z == c) + (v.w == c);
        }
    }

    __shared__ int lds[4][NCLS];        // 4 waves per block
    const int wave = threadIdx.x >> 6;
    const int lane = threadIdx.x & 63;
#pragma unroll
    for (int c = 0; c < NCLS; ++c) {
        int s = cnt[c];
#pragma unroll
        for (int off = 32; off > 0; off >>= 1) s += __shfl_down(s, off);
        if (lane == 0) lds[wave][c] = s;
    }
    __syncthreads();
    if (threadIdx.x < NCLS) {
        const int c = threadIdx.x;
        partial[blockIdx.x * NCLS + c] =
            lds[0][c] + lds[1][c] + lds[2][c] + lds[3][c];
    }
}

// ---------------------------------------------------------------------------
// Kernel 2 (fused): reduce partials -> weights in LDS, then stream-scale.
// Phase 0: threads t<144 compute hist[b][c] (64 L2-resident loads each) into
//          LDS, barrier, then redundantly compute per-sample stats and the
//          weight -> wsm[144]. Matches the numpy reference:
//            p = h/total; logh = (h>0) ? -log(p) : 0
//            mean/std over bins with h>0 (population variance, ddof=0)
//            weight = (logh != 0) ? (logh-mean)/std*0.1 + 1.0 : 1.0
// Phase 1: grid-stride float4 scale; plane = i>>16 (65536 float4s per plane).
// ---------------------------------------------------------------------------
__global__ void __launch_bounds__(256) fused_weight_scale_kernel(
        const int* __restrict__ partial,
        const float4* __restrict__ in,
        float4* __restrict__ out,
        int n4) {
    __shared__ float hsm[NB * NCLS];
    __shared__ float wsm[NB * NCLS];
    const int t = threadIdx.x;

    if (t < NB * NCLS) {
        const int b = t / NCLS;
        const int c = t % NCLS;
        // hist[b][c] = sum over this sample's 64 block-partials
        const int* p = partial + b * (BLKS_PER_SAMPLE * NCLS) + c;
        int s = 0;
#pragma unroll
        for (int k = 0; k < BLKS_PER_SAMPLE; ++k) s += p[k * NCLS];
        hsm[t] = (float)s;
    }
    __syncthreads();

    if (t < NB * NCLS) {
        const int b = t / NCLS;
        const int c = t % NCLS;
        float h[NCLS];
        float total = 0.f;
#pragma unroll
        for (int k = 0; k < NCLS; ++k) {
            h[k] = hsm[b * NCLS + k];
            total += h[k];
        }
        float logh[NCLS];
        float cntbins = 0.f, sum = 0.f;
#pragma unroll
        for (int k = 0; k < NCLS; ++k) {
            float p = h[k] / total;
            float lg = (h[k] > 0.f) ? -logf(p) : 0.f;
            logh[k] = lg;
            if (h[k] > 0.f) { cntbins += 1.f; sum += lg; }
        }
        const float mean = sum / cntbins;
        float var = 0.f;
#pragma unroll
        for (int k = 0; k < NCLS; ++k) {
            if (h[k] > 0.f) {
                float d = logh[k] - mean;
                var += d * d;
            }
        }
        var /= cntbins;
        const float stdv = sqrtf(var);
        const float lc = logh[c];
        wsm[t] = (lc != 0.f) ? (lc - mean) / stdv * 0.1f + 1.0f : 1.0f;
    }
    __syncthreads();

    // Phase 1: streaming scale. Each (b,c) plane is 512*512/4 = 65536 float4s.
    const int stride = gridDim.x * 256;
    for (int i = blockIdx.x * 256 + t; i < n4; i += stride) {
        const float w = wsm[i >> 16];
        float4 v = in[i];
        v.x *= w; v.y *= w; v.z *= w; v.w *= w;
        out[i] = v;
    }
}

extern "C" void kernel_launch(void* const* d_in, const int* in_sizes, int n_in,
                              void* d_out, int out_size, void* d_ws, size_t ws_size,
                              hipStream_t stream) {
    const float* preds = (const float*)d_in[0];   // [16,9,512,512] f32
    const int* labels = (const int*)d_in[1];      // [16,512,512] i32
    float* out = (float*)d_out;

    // Workspace: partial[1024][9] ints (fully overwritten each call -> no init)
    int* partial = (int*)d_ws;

    hist_kernel<<<NBLK_HIST, 256, 0, stream>>>(labels, partial);

    const int n4 = (NB * NCLS * HW) / 4;   // 9437184 float4s
    fused_weight_scale_kernel<<<2048, 256, 0, stream>>>(
        partial, (const float4*)preds, (float4*)out, n4);
}